// Round 5
// baseline (319.835 us; speedup 1.0000x reference)
//
#include <hip/hip_runtime.h>
#include <cstdint>
#include <cstddef>

namespace {
constexpr int Bn = 8, Dn = 512, Hn = 96, Wn = 96, HWn = Hn * Wn; // 9216
constexpr int Cn = 8, Kn = 10, CKn = Cn * Kn;                    // 80
constexpr int NPIX = Bn * HWn;                                   // 73728
constexpr int NMOM = 66;                                         // vm, 10 S_k, 55 S_kl
constexpr int RSTRIP = 8;                                        // output rows per pool block
constexpr float EPSF = 1e-8f;
constexpr float MINM = 0.05f;

// workspace layout (floats)
constexpr size_t oPnT = 0;                                 // [D][CK] 40960
constexpr size_t oS   = oPnT + (size_t)Dn * CKn;           // [B][K][HW] 737280
constexpr size_t oMom = oS + (size_t)Bn * Kn * HWn;        // [BC][66] (zeroed)
constexpr size_t oCnt = oMom + 64 * NMOM;                  // [BC] int (zeroed)
constexpr size_t oEnd = oCnt + 64;
} // namespace

__device__ __forceinline__ float wred64(float v) {
#pragma unroll
    for (int o = 32; o > 0; o >>= 1) v += __shfl_down(v, o, 64);
    return v;
}

// ---------------------------------------------------------------------------
// K0: normalize prototypes, store transposed PnT[d][ck]
__global__ __launch_bounds__(64) void k_protonorm(const float* __restrict__ P,
                                                  float* __restrict__ PnT) {
    int ck = blockIdx.x, lane = threadIdx.x;
    float v[8]; float ss = 0.f;
#pragma unroll
    for (int j = 0; j < 8; ++j) { v[j] = P[ck * Dn + lane + 64 * j]; ss += v[j] * v[j]; }
    ss = wred64(ss);
    ss = __shfl(ss, 0, 64);
    float inv = 1.0f / fmaxf(sqrtf(ss), 1e-12f);
#pragma unroll
    for (int j = 0; j < 8; ++j)
        PnT[(size_t)(lane + 64 * j) * CKn + ck] = v[j] * inv;
}

// ---------------------------------------------------------------------------
// K1: fused sim. 64 pixels/block, 4 waves each own a 128-d chunk of those
// pixels; LDS 4-way reduce; normalize; write S[b][k][hw]; class histogram.
__global__ __launch_bounds__(256) void k_sim(const float* __restrict__ F,
                                             const float* __restrict__ PnT,
                                             const int* __restrict__ mask,
                                             float* __restrict__ S,
                                             int* __restrict__ cnt) {
    __shared__ float pch[64 * 96]; // proto stage [sd][c*12+k]; reused as redbuf
    __shared__ int hist[Cn];
    const int tid = threadIdx.x;
    const int pixLocal = tid & 63;
    const int g = tid >> 6;                  // d-chunk 0..3
    const int pix = blockIdx.x * 64 + pixLocal;
    const int b = pix / HWn, hw = pix % HWn;
    if (tid < Cn) hist[tid] = 0;

    const int m = mask[pix];
    const int cc = m > 0 ? m - 1 : 0;

    float acc[Kn]; float ss = 0.f;
#pragma unroll
    for (int k = 0; k < Kn; ++k) acc[k] = 0.f;

    for (int p = 0; p < 8; ++p) {
        __syncthreads();
        // stage 16 rows per d-chunk: sd = sg*16+dd -> global d = sg*128+p*16+dd
        for (int i = tid; i < 64 * CKn; i += 256) {
            int sd = i / CKn, ck = i % CKn;
            int sg = sd >> 4, dd = sd & 15;
            int gd = sg * 128 + p * 16 + dd;
            int c = ck / Kn, kk = ck % Kn;
            pch[sd * 96 + c * 12 + kk] = PnT[(size_t)gd * CKn + ck];
        }
        __syncthreads();
        const float* Fp = &F[(size_t)(b * Dn + g * 128 + p * 16) * HWn + hw];
#pragma unroll
        for (int dd = 0; dd < 16; ++dd) {
            float f = Fp[(size_t)dd * HWn];
            ss += f * f;
            const float4* p4 = (const float4*)&pch[(g * 16 + dd) * 96 + cc * 12];
            float4 pa = p4[0], pb = p4[1];
            float2 pc = *(const float2*)&pch[(g * 16 + dd) * 96 + cc * 12 + 8];
            acc[0] += f * pa.x; acc[1] += f * pa.y; acc[2] += f * pa.z; acc[3] += f * pa.w;
            acc[4] += f * pb.x; acc[5] += f * pb.y; acc[6] += f * pb.z; acc[7] += f * pb.w;
            acc[8] += f * pc.x; acc[9] += f * pc.y;
        }
    }
    __syncthreads();
    // 4-way cross-wave reduce via LDS: redbuf[g][pixLocal][12]
    float* red = pch;
#pragma unroll
    for (int k = 0; k < Kn; ++k) red[g * 768 + pixLocal * 12 + k] = acc[k];
    red[g * 768 + pixLocal * 12 + 10] = ss;
    __syncthreads();
    if (tid < 64) {
        float tot[11];
#pragma unroll
        for (int j = 0; j < 11; ++j)
            tot[j] = red[tid * 12 + j] + red[768 + tid * 12 + j] +
                     red[1536 + tid * 12 + j] + red[2304 + tid * 12 + j];
        float inv = 1.0f / fmaxf(sqrtf(tot[10]), 1e-12f);
#pragma unroll
        for (int k = 0; k < Kn; ++k)
            S[(size_t)(b * Kn + k) * HWn + hw] = tot[k] * inv;
        if (m > 0) atomicAdd(&hist[m - 1], 1);
    }
    __syncthreads();
    if (tid < Cn) atomicAdd(&cnt[((blockIdx.x * 64) / HWn) * Cn + tid], hist[tid]);
}

// ---------------------------------------------------------------------------
// K2: fused pool. Block = (bc, 8-row strip). Phase 1: horizontal 7-pool of
// the 14 needed rows into LDS (zero-filled outside image). Phase 2: vertical
// 7-pool from LDS + thread-local raw moments -> block reduce -> atomics.
__global__ __launch_bounds__(256) void k_pool(const int* __restrict__ mask,
                                              const float* __restrict__ S,
                                              float* __restrict__ mom) {
    __shared__ float sNum[Kn][14 * 96]; // 52.5 KB
    __shared__ float sDen[14 * 96];     // 5.25 KB
    __shared__ float red[4][NMOM];
    const int bc = blockIdx.x / 12, strip = blockIdx.x % 12;
    const int c = bc & 7, b = bc >> 3;
    const int h0 = strip * RSTRIP;
    const int tid = threadIdx.x;

    // ---- phase 1: H-pool rows h0-3 .. h0+10 into LDS (groups of 4 along w)
    for (int item = tid; item < 14 * 24; item += 256) {
        const int r = item / 24, wg = item % 24;
        const int hh = h0 - 3 + r;
        const int w0 = wg * 4;
        float a[Kn][4];
        float dn[4] = {0.f, 0.f, 0.f, 0.f};
#pragma unroll
        for (int k = 0; k < Kn; ++k)
#pragma unroll
            for (int o = 0; o < 4; ++o) a[k][o] = 0.f;

        if (hh >= 0 && hh < Hn) {
            const int rowb = b * HWn + hh * Wn;
            const float* Srow = &S[(size_t)b * Kn * HWn + hh * Wn];
#pragma unroll
            for (int dc = -3; dc <= 6; ++dc) {
                int ww = w0 + dc;
                if (ww < 0 || ww >= Wn) continue;
                const int olo = dc - 3 > 0 ? dc - 3 : 0;
                const int ohi = dc + 3 < 3 ? dc + 3 : 3;
                if (mask[rowb + ww] == c + 1) {
#pragma unroll
                    for (int o = 0; o < 4; ++o)
                        if (o >= olo && o <= ohi) dn[o] += 1.0f;
#pragma unroll
                    for (int k = 0; k < Kn; ++k) {
                        float s = Srow[(size_t)k * HWn + ww];
#pragma unroll
                        for (int o = 0; o < 4; ++o)
                            if (o >= olo && o <= ohi) a[k][o] += s;
                    }
                }
            }
        }
#pragma unroll
        for (int o = 0; o < 4; ++o) {
            sDen[r * 96 + w0 + o] = dn[o];
#pragma unroll
            for (int k = 0; k < Kn; ++k) sNum[k][r * 96 + w0 + o] = a[k][o];
        }
    }
    __syncthreads();

    // ---- phase 2: V-pool + moments (zero rows outside image are exact +0)
    float mm[NMOM];
#pragma unroll
    for (int i = 0; i < NMOM; ++i) mm[i] = 0.f;

    for (int out = tid; out < RSTRIP * 96; out += 256) {
        const int oh = out / 96, w = out % 96;
        float den = 0.f;
        float n[Kn];
#pragma unroll
        for (int k = 0; k < Kn; ++k) n[k] = 0.f;
#pragma unroll
        for (int dr = 0; dr < 7; ++dr) {
            const int r = oh + dr;
            den += sDen[r * 96 + w];
#pragma unroll
            for (int k = 0; k < Kn; ++k) n[k] += sNum[k][r * 96 + w];
        }
        float dA = den * (1.0f / 49.0f);
        float inv = 1.0f / (dA + EPSF);
        float vm = (dA > MINM) ? 1.0f : 0.0f;
        float rr[Kn];
#pragma unroll
        for (int k = 0; k < Kn; ++k)
            rr[k] = n[k] * (1.0f / 49.0f) * inv * vm; // pre-masked
        mm[0] += vm;
#pragma unroll
        for (int k = 0; k < Kn; ++k) mm[1 + k] += rr[k];
        int p = 11;
#pragma unroll
        for (int k = 0; k < Kn; ++k)
#pragma unroll
            for (int l = 0; l <= k; ++l, ++p) mm[p] += rr[k] * rr[l];
    }

    // ---- block reduce 66 moments -> atomics
    const int lane = tid & 63, wv = tid >> 6;
#pragma unroll
    for (int i = 0; i < NMOM; ++i) {
        float x = wred64(mm[i]);
        if (lane == 0) red[wv][i] = x;
    }
    __syncthreads();
    for (int i = tid; i < NMOM; i += 256)
        atomicAdd(&mom[bc * NMOM + i],
                  red[0][i] + red[1][i] + red[2][i] + red[3][i]);
}

// ---------------------------------------------------------------------------
// K3: finalize from raw moments: M[kl] = S_kl - S_k S_l / Vf, loss, scalar
__global__ __launch_bounds__(64) void k_final(const float* __restrict__ mom,
                                              const int* __restrict__ cnt,
                                              float* __restrict__ out) {
    const int bc = threadIdx.x; // 0..63
    float mo[NMOM];
#pragma unroll
    for (int i = 0; i < NMOM; ++i) mo[i] = mom[bc * NMOM + i];
    const float V = mo[0];
    const float Vf = fmaxf(V, 1.0f);
    float Sk[Kn];
#pragma unroll
    for (int k = 0; k < Kn; ++k) Sk[k] = mo[1 + k];

    float M[55];
    {
        int p = 0;
#pragma unroll
        for (int k = 0; k < Kn; ++k)
#pragma unroll
            for (int l = 0; l <= k; ++l, ++p)
                M[p] = mo[11 + p] - Sk[k] * Sk[l] / Vf;
    }
    float nrm[Kn];
#pragma unroll
    for (int k = 0; k < Kn; ++k)
        nrm[k] = sqrtf(fmaxf(M[k * (k + 1) / 2 + k], 0.0f));
    float loss = 0.f;
    {
        int p = 0;
#pragma unroll
        for (int k = 0; k < Kn; ++k) {
#pragma unroll
            for (int l = 0; l <= k; ++l, ++p) {
                if (l == k) continue;
                float g = M[p] / ((nrm[k] + EPSF) * (nrm[l] + EPSF)) / Vf;
                loss += 2.0f * g * g;
            }
        }
    }
    loss *= 1.0f / (float)(Kn * (Kn - 1));
    bool act = (cnt[bc] >= 1) && (V >= 2.0f);
    float sl = act ? loss : 0.f;
    float sa = act ? 1.f : 0.f;
#pragma unroll
    for (int o = 4; o > 0; o >>= 1) {
        sl += __shfl_down(sl, o, 8);
        sa += __shfl_down(sa, o, 8);
    }
    __shared__ float pimg[Bn];
    if ((bc & 7) == 0) pimg[bc >> 3] = sl / fmaxf(sa, 1.0f);
    __syncthreads();
    if (bc == 0) {
        float tot = 0.f;
#pragma unroll
        for (int b = 0; b < Bn; ++b) tot += pimg[b];
        out[0] = tot / (float)Bn;
    }
}

// ---------------------------------------------------------------------------
extern "C" void kernel_launch(void* const* d_in, const int* in_sizes, int n_in,
                              void* d_out, int out_size, void* d_ws, size_t ws_size,
                              hipStream_t stream) {
    const float* F  = (const float*)d_in[0];
    const float* P  = (const float*)d_in[1];
    const int* mask = (const int*)d_in[2];
    float* ws = (float*)d_ws;
    float* out = (float*)d_out;

    hipMemsetAsync(ws + oMom, 0, (oEnd - oMom) * sizeof(float), stream);

    k_protonorm<<<CKn, 64, 0, stream>>>(P, ws + oPnT);
    k_sim<<<NPIX / 64, 256, 0, stream>>>(F, ws + oPnT, mask, ws + oS,
                                         (int*)(ws + oCnt));
    k_pool<<<64 * 12, 256, 0, stream>>>(mask, ws + oS, ws + oMom);
    k_final<<<1, 64, 0, stream>>>(ws + oMom, (const int*)(ws + oCnt), out);
}

// Round 6
// 287.008 us; speedup vs baseline: 1.1144x; 1.1144x over previous
//
#include <hip/hip_runtime.h>
#include <cstdint>
#include <cstddef>

namespace {
constexpr int Bn = 8, Dn = 512, Hn = 96, Wn = 96, HWn = Hn * Wn; // 9216
constexpr int Cn = 8, Kn = 10, CKn = Cn * Kn;                    // 80
constexpr int NPIX = Bn * HWn;                                   // 73728
constexpr int NCHUNK = 4, DCH = Dn / NCHUNK;                     // 4 x 128
constexpr int NMOM = 66;                                         // vm, 10 S_k, 55 S_kl
constexpr int RSTRIP = 8;                                        // output rows per pool block
constexpr int PROW = 96;                                         // padded proto row: c*12+k
constexpr float EPSF = 1e-8f;
constexpr float MINM = 0.05f;

// workspace layout (floats)
constexpr size_t oPnTp = 0;                                  // [D][96] padded 49152
constexpr size_t oS    = oPnTp + (size_t)Dn * PROW;          // [B][K][HW] 737280
constexpr size_t oPart = oS + (size_t)Bn * Kn * HWn;         // [chunk][11][NPIX] 3244032
constexpr size_t oMom  = oPart + (size_t)NCHUNK * 11 * NPIX; // [BC][66] (zeroed)
constexpr size_t oCnt  = oMom + 64 * NMOM;                   // [BC] int (zeroed)
constexpr size_t oEnd  = oCnt + 64;
} // namespace

__device__ __forceinline__ float wred64(float v) {
#pragma unroll
    for (int o = 32; o > 0; o >>= 1) v += __shfl_down(v, o, 64);
    return v;
}

// ---------------------------------------------------------------------------
// K0: normalize prototypes, write PADDED transposed layout PnTp[d][c*12+k]
// so k_sim staging is a raw float4 copy with zero index math.
__global__ __launch_bounds__(64) void k_protonorm(const float* __restrict__ P,
                                                  float* __restrict__ PnTp) {
    int ck = blockIdx.x, lane = threadIdx.x;
    const int c = ck / Kn, kk = ck % Kn;
    float v[8]; float ss = 0.f;
#pragma unroll
    for (int j = 0; j < 8; ++j) { v[j] = P[ck * Dn + lane + 64 * j]; ss += v[j] * v[j]; }
    ss = wred64(ss);
    ss = __shfl(ss, 0, 64);
    float inv = 1.0f / fmaxf(sqrtf(ss), 1e-12f);
#pragma unroll
    for (int j = 0; j < 8; ++j)
        PnTp[(size_t)(lane + 64 * j) * PROW + c * 12 + kk] = v[j] * inv;
}

// ---------------------------------------------------------------------------
// K1: split-D partial sims. grid (288 pixel-blocks, 4 d-chunks).
// Staging is a contiguous float4 copy of the pre-padded prototype rows.
__global__ __launch_bounds__(256) void k_sim(const float* __restrict__ F,
                                             const float* __restrict__ PnTp,
                                             float* __restrict__ part,
                                             const int* __restrict__ mask) {
    __shared__ float pch[64 * PROW]; // [dd][c*12+k], 24.6 KB
    const int tid = threadIdx.x;
    const int pix = blockIdx.x * 256 + tid;
    const int chunk = blockIdx.y;
    const int b = pix / HWn, hw = pix % HWn;

    const int m = mask[pix];
    const int cc = m > 0 ? m - 1 : 0;

    float acc[Kn]; float ss = 0.f;
#pragma unroll
    for (int k = 0; k < Kn; ++k) acc[k] = 0.f;

    for (int p = 0; p < DCH / 64; ++p) {
        const int dbase = chunk * DCH + p * 64;
        __syncthreads();
        {   // raw vector copy: 64 rows x 96 floats = 1536 float4s
            const float4* src = (const float4*)&PnTp[(size_t)dbase * PROW];
            float4* dst = (float4*)pch;
#pragma unroll
            for (int i = 0; i < 6; ++i)
                dst[tid + 256 * i] = src[tid + 256 * i];
        }
        __syncthreads();
#pragma unroll 4
        for (int dd = 0; dd < 64; ++dd) {
            float f = F[(size_t)(b * Dn + dbase + dd) * HWn + hw];
            ss += f * f;
            const float4* p4 = (const float4*)&pch[dd * PROW + cc * 12];
            float4 pa = p4[0], pb = p4[1];
            float2 pc = *(const float2*)&pch[dd * PROW + cc * 12 + 8];
            acc[0] += f * pa.x; acc[1] += f * pa.y; acc[2] += f * pa.z; acc[3] += f * pa.w;
            acc[4] += f * pb.x; acc[5] += f * pb.y; acc[6] += f * pb.z; acc[7] += f * pb.w;
            acc[8] += f * pc.x; acc[9] += f * pc.y;
        }
    }
#pragma unroll
    for (int k = 0; k < Kn; ++k)
        part[(size_t)(chunk * 11 + k) * NPIX + pix] = acc[k];
    part[(size_t)(chunk * 11 + 10) * NPIX + pix] = ss;
}

// ---------------------------------------------------------------------------
// K2: reduce chunks, normalize, write S[b][k][hw]; class histogram.
__global__ __launch_bounds__(256) void k_simred(const float* __restrict__ part,
                                                const int* __restrict__ mask,
                                                float* __restrict__ S,
                                                int* __restrict__ cnt) {
    __shared__ int hist[Cn];
    const int tid = threadIdx.x;
    const int pix = blockIdx.x * 256 + tid;
    if (tid < Cn) hist[tid] = 0;
    __syncthreads();

    float acc[Kn]; float ss = 0.f;
#pragma unroll
    for (int k = 0; k < Kn; ++k) acc[k] = 0.f;
#pragma unroll
    for (int ch = 0; ch < NCHUNK; ++ch) {
#pragma unroll
        for (int k = 0; k < Kn; ++k)
            acc[k] += part[(size_t)(ch * 11 + k) * NPIX + pix];
        ss += part[(size_t)(ch * 11 + 10) * NPIX + pix];
    }
    float inv = 1.0f / fmaxf(sqrtf(ss), 1e-12f);
    const int b = pix / HWn, hw = pix % HWn;
#pragma unroll
    for (int k = 0; k < Kn; ++k)
        S[(size_t)(b * Kn + k) * HWn + hw] = acc[k] * inv;

    const int m = mask[pix];
    if (m > 0) atomicAdd(&hist[m - 1], 1);
    __syncthreads();
    if (tid < Cn) atomicAdd(&cnt[(pix / HWn) * Cn + tid], hist[tid]);
}

// ---------------------------------------------------------------------------
// K3: fused pool. Block = (bc, 8-row strip). Phase 1: horizontal 7-pool of
// the 14 needed rows into LDS (zero-filled outside image; mask-miss taps
// skipped — exact, adding s*0 == +0.0). Phase 2: vertical 7-pool from LDS +
// thread-local raw moments -> block reduce -> atomics.
__global__ __launch_bounds__(256) void k_pool(const int* __restrict__ mask,
                                              const float* __restrict__ S,
                                              float* __restrict__ mom) {
    __shared__ float sNum[Kn][14 * 96]; // 52.5 KB
    __shared__ float sDen[14 * 96];     // 5.25 KB
    __shared__ float red[4][NMOM];
    const int bc = blockIdx.x / 12, strip = blockIdx.x % 12;
    const int c = bc & 7, b = bc >> 3;
    const int h0 = strip * RSTRIP;
    const int tid = threadIdx.x;

    // ---- phase 1: H-pool rows h0-3 .. h0+10 into LDS (groups of 4 along w)
    for (int item = tid; item < 14 * 24; item += 256) {
        const int r = item / 24, wg = item % 24;
        const int hh = h0 - 3 + r;
        const int w0 = wg * 4;
        float a[Kn][4];
        float dn[4] = {0.f, 0.f, 0.f, 0.f};
#pragma unroll
        for (int k = 0; k < Kn; ++k)
#pragma unroll
            for (int o = 0; o < 4; ++o) a[k][o] = 0.f;

        if (hh >= 0 && hh < Hn) {
            const int rowb = b * HWn + hh * Wn;
            const float* Srow = &S[(size_t)b * Kn * HWn + hh * Wn];
#pragma unroll
            for (int dc = -3; dc <= 6; ++dc) {
                int ww = w0 + dc;
                if (ww < 0 || ww >= Wn) continue;
                const int olo = dc - 3 > 0 ? dc - 3 : 0;
                const int ohi = dc + 3 < 3 ? dc + 3 : 3;
                if (mask[rowb + ww] == c + 1) {
#pragma unroll
                    for (int o = 0; o < 4; ++o)
                        if (o >= olo && o <= ohi) dn[o] += 1.0f;
#pragma unroll
                    for (int k = 0; k < Kn; ++k) {
                        float s = Srow[(size_t)k * HWn + ww];
#pragma unroll
                        for (int o = 0; o < 4; ++o)
                            if (o >= olo && o <= ohi) a[k][o] += s;
                    }
                }
            }
        }
#pragma unroll
        for (int o = 0; o < 4; ++o) {
            sDen[r * 96 + w0 + o] = dn[o];
#pragma unroll
            for (int k = 0; k < Kn; ++k) sNum[k][r * 96 + w0 + o] = a[k][o];
        }
    }
    __syncthreads();

    // ---- phase 2: V-pool + moments (zero rows outside image are exact +0)
    float mm[NMOM];
#pragma unroll
    for (int i = 0; i < NMOM; ++i) mm[i] = 0.f;

    for (int out = tid; out < RSTRIP * 96; out += 256) {
        const int oh = out / 96, w = out % 96;
        float den = 0.f;
        float n[Kn];
#pragma unroll
        for (int k = 0; k < Kn; ++k) n[k] = 0.f;
#pragma unroll
        for (int dr = 0; dr < 7; ++dr) {
            const int r = oh + dr;
            den += sDen[r * 96 + w];
#pragma unroll
            for (int k = 0; k < Kn; ++k) n[k] += sNum[k][r * 96 + w];
        }
        float dA = den * (1.0f / 49.0f);
        float inv = 1.0f / (dA + EPSF);
        float vm = (dA > MINM) ? 1.0f : 0.0f;
        float rr[Kn];
#pragma unroll
        for (int k = 0; k < Kn; ++k)
            rr[k] = n[k] * (1.0f / 49.0f) * inv * vm; // pre-masked
        mm[0] += vm;
#pragma unroll
        for (int k = 0; k < Kn; ++k) mm[1 + k] += rr[k];
        int p = 11;
#pragma unroll
        for (int k = 0; k < Kn; ++k)
#pragma unroll
            for (int l = 0; l <= k; ++l, ++p) mm[p] += rr[k] * rr[l];
    }

    // ---- block reduce 66 moments -> atomics
    const int lane = tid & 63, wv = tid >> 6;
#pragma unroll
    for (int i = 0; i < NMOM; ++i) {
        float x = wred64(mm[i]);
        if (lane == 0) red[wv][i] = x;
    }
    __syncthreads();
    for (int i = tid; i < NMOM; i += 256)
        atomicAdd(&mom[bc * NMOM + i],
                  red[0][i] + red[1][i] + red[2][i] + red[3][i]);
}

// ---------------------------------------------------------------------------
// K4: finalize from raw moments: M[kl] = S_kl - S_k S_l / Vf, loss, scalar
__global__ __launch_bounds__(64) void k_final(const float* __restrict__ mom,
                                              const int* __restrict__ cnt,
                                              float* __restrict__ out) {
    const int bc = threadIdx.x; // 0..63
    float mo[NMOM];
#pragma unroll
    for (int i = 0; i < NMOM; ++i) mo[i] = mom[bc * NMOM + i];
    const float V = mo[0];
    const float Vf = fmaxf(V, 1.0f);
    float Sk[Kn];
#pragma unroll
    for (int k = 0; k < Kn; ++k) Sk[k] = mo[1 + k];

    float M[55];
    {
        int p = 0;
#pragma unroll
        for (int k = 0; k < Kn; ++k)
#pragma unroll
            for (int l = 0; l <= k; ++l, ++p)
                M[p] = mo[11 + p] - Sk[k] * Sk[l] / Vf;
    }
    float nrm[Kn];
#pragma unroll
    for (int k = 0; k < Kn; ++k)
        nrm[k] = sqrtf(fmaxf(M[k * (k + 1) / 2 + k], 0.0f));
    float loss = 0.f;
    {
        int p = 0;
#pragma unroll
        for (int k = 0; k < Kn; ++k) {
#pragma unroll
            for (int l = 0; l <= k; ++l, ++p) {
                if (l == k) continue;
                float g = M[p] / ((nrm[k] + EPSF) * (nrm[l] + EPSF)) / Vf;
                loss += 2.0f * g * g;
            }
        }
    }
    loss *= 1.0f / (float)(Kn * (Kn - 1));
    bool act = (cnt[bc] >= 1) && (V >= 2.0f);
    float sl = act ? loss : 0.f;
    float sa = act ? 1.f : 0.f;
#pragma unroll
    for (int o = 4; o > 0; o >>= 1) {
        sl += __shfl_down(sl, o, 8);
        sa += __shfl_down(sa, o, 8);
    }
    __shared__ float pimg[Bn];
    if ((bc & 7) == 0) pimg[bc >> 3] = sl / fmaxf(sa, 1.0f);
    __syncthreads();
    if (bc == 0) {
        float tot = 0.f;
#pragma unroll
        for (int b = 0; b < Bn; ++b) tot += pimg[b];
        out[0] = tot / (float)Bn;
    }
}

// ---------------------------------------------------------------------------
extern "C" void kernel_launch(void* const* d_in, const int* in_sizes, int n_in,
                              void* d_out, int out_size, void* d_ws, size_t ws_size,
                              hipStream_t stream) {
    const float* F  = (const float*)d_in[0];
    const float* P  = (const float*)d_in[1];
    const int* mask = (const int*)d_in[2];
    float* ws = (float*)d_ws;
    float* out = (float*)d_out;

    hipMemsetAsync(ws + oMom, 0, (oEnd - oMom) * sizeof(float), stream);

    k_protonorm<<<CKn, 64, 0, stream>>>(P, ws + oPnTp);
    k_sim<<<dim3(NPIX / 256, NCHUNK), 256, 0, stream>>>(F, ws + oPnTp,
                                                        ws + oPart, mask);
    k_simred<<<NPIX / 256, 256, 0, stream>>>(ws + oPart, mask, ws + oS,
                                             (int*)(ws + oCnt));
    k_pool<<<64 * 12, 256, 0, stream>>>(mask, ws + oS, ws + oMom);
    k_final<<<1, 64, 0, stream>>>(ws + oMom, (const int*)(ws + oCnt), out);
}